// Round 2
// baseline (744.678 us; speedup 1.0000x reference)
//
#include <hip/hip_runtime.h>
#include <cstdint>
#include <cstddef>

// ---------------------------------------------------------------------------
// GEMM: C[M,128] = A[M,128] @ B[128,128], fp32 vector ALU, 64x64 LDS tiles.
// ---------------------------------------------------------------------------
__global__ void gemm128_f32(const float* __restrict__ A, const float* __restrict__ B,
                            float* __restrict__ C, int M) {
  __shared__ float As[64][132];   // +4 pad: breaks power-of-2 bank stride
  __shared__ float Bs[128][68];
  const int t = threadIdx.x;      // 256 threads
  const int row0 = blockIdx.x * 64;
  const int col0 = blockIdx.y * 64;

  // Load A tile: 64 rows x 128 cols = 2048 float4
#pragma unroll
  for (int i = 0; i < 8; ++i) {
    int idx = t + i * 256;
    int r = idx >> 5, c4 = idx & 31;
    float4 v = make_float4(0.f, 0.f, 0.f, 0.f);
    if (row0 + r < M) v = *reinterpret_cast<const float4*>(A + (size_t)(row0 + r) * 128 + c4 * 4);
    *reinterpret_cast<float4*>(&As[r][c4 * 4]) = v;
  }
  // Load B tile: 128 rows x 64 cols = 2048 float4
#pragma unroll
  for (int i = 0; i < 8; ++i) {
    int idx = t + i * 256;
    int k = idx >> 4, c4 = idx & 15;
    *reinterpret_cast<float4*>(&Bs[k][c4 * 4]) =
        *reinterpret_cast<const float4*>(B + (size_t)k * 128 + col0 + c4 * 4);
  }
  __syncthreads();

  const int ty = t >> 4, tx = t & 15;
  float acc[4][4] = {};
#pragma unroll 8
  for (int k = 0; k < 128; ++k) {
    float a[4];
#pragma unroll
    for (int i = 0; i < 4; ++i) a[i] = As[ty * 4 + i][k];
    float4 bv = *reinterpret_cast<float4*>(&Bs[k][tx * 4]);
    float b[4] = {bv.x, bv.y, bv.z, bv.w};
#pragma unroll
    for (int i = 0; i < 4; ++i)
#pragma unroll
      for (int j = 0; j < 4; ++j) acc[i][j] += a[i] * b[j];
  }
#pragma unroll
  for (int i = 0; i < 4; ++i) {
    int r = row0 + ty * 4 + i;
    if (r < M) {
      float4 v = make_float4(acc[i][0], acc[i][1], acc[i][2], acc[i][3]);
      *reinterpret_cast<float4*>(C + (size_t)r * 128 + col0 + tx * 4) = v;
    }
  }
}

// ---------------------------------------------------------------------------
// CSR build: degree count -> single-block scan -> scatter (permuted src ids +
// edge->csr-position map so all later per-edge data is CSR-ordered).
// ---------------------------------------------------------------------------
__global__ void count_deg(const int* __restrict__ trg, int* __restrict__ deg, int E) {
  int e = blockIdx.x * blockDim.x + threadIdx.x;
  if (e < E) atomicAdd(&deg[trg[e]], 1);
}

__global__ void scan_offsets(const int* __restrict__ deg, int* __restrict__ row_off, int N) {
  __shared__ int sums[1024];
  const int t = threadIdx.x;
  const int per = (N + 1023) / 1024;
  const int beg = t * per;
  const int end = (beg + per < N) ? beg + per : N;
  int s = 0;
  for (int i = beg; i < end; ++i) s += deg[i];
  sums[t] = s;
  __syncthreads();
  // Hillis-Steele inclusive scan over 1024 partials
  for (int off = 1; off < 1024; off <<= 1) {
    int v = sums[t];
    int add = (t >= off) ? sums[t - off] : 0;
    __syncthreads();
    sums[t] = v + add;
    __syncthreads();
  }
  int excl = (t == 0) ? 0 : sums[t - 1];
  for (int i = beg; i < end; ++i) {
    row_off[i] = excl;
    excl += deg[i];
  }
  if (t == 1023) row_off[N] = sums[1023];
}

__global__ void scatter_csr(const int* __restrict__ src, const int* __restrict__ trg,
                            const int* __restrict__ row_off, int* __restrict__ cursor,
                            int* __restrict__ srcp, int* __restrict__ epos, int E) {
  int e = blockIdx.x * blockDim.x + threadIdx.x;
  if (e >= E) return;
  int n = trg[e];
  int pos = row_off[n] + atomicAdd(&cursor[n], 1);
  srcp[pos] = src[e];
  epos[e] = pos;
}

// ---------------------------------------------------------------------------
// Per-node attention scores: s_src[n,h] = <proj[n,h,:], a_src[h,:]>, same for trg
// ---------------------------------------------------------------------------
template <int H, int F>
__global__ void node_scores(const float* __restrict__ proj, const float* __restrict__ a_src,
                            const float* __restrict__ a_trg, float* __restrict__ ssrc,
                            float* __restrict__ strg, int N) {
  int idx = blockIdx.x * blockDim.x + threadIdx.x;
  if (idx >= N * H) return;
  int n = idx / H, h = idx % H;
  const float* p = proj + (size_t)n * (H * F) + h * F;
  const float* as = a_src + h * F;
  const float* at = a_trg + h * F;
  float d1 = 0.f, d2 = 0.f;
#pragma unroll
  for (int f = 0; f < F; f += 4) {
    float4 pv = *reinterpret_cast<const float4*>(p + f);
    float4 av = *reinterpret_cast<const float4*>(as + f);
    float4 tv = *reinterpret_cast<const float4*>(at + f);
    d1 += pv.x * av.x + pv.y * av.y + pv.z * av.z + pv.w * av.w;
    d2 += pv.x * tv.x + pv.y * tv.y + pv.z * tv.z + pv.w * tv.w;
  }
  ssrc[idx] = d1;
  strg[idx] = d2;
}

// ---------------------------------------------------------------------------
// Per-edge: exp(leaky_relu(s_src[src]+s_trg[trg]+ep*c_h)), written in CSR
// order via epos. Global-max shift cancels in the softmax ratio -> skipped.
// ---------------------------------------------------------------------------
template <int H, int F>
__global__ void edge_scores(const int* __restrict__ src, const int* __restrict__ trg,
                            const int* __restrict__ epos, const float* __restrict__ ep,
                            const float* __restrict__ Wt, const float* __restrict__ a_tp,
                            const float* __restrict__ ssrc, const float* __restrict__ strg,
                            float* __restrict__ exps, int E) {
  __shared__ float c[H];
  if (threadIdx.x < H) {
    float a = 0.f;
    for (int f = 0; f < F; ++f) a += Wt[threadIdx.x * F + f] * a_tp[threadIdx.x * F + f];
    c[threadIdx.x] = a;
  }
  __syncthreads();
  int e = blockIdx.x * blockDim.x + threadIdx.x;
  if (e >= E) return;
  int s = src[e], g = trg[e];
  float p = ep[e];
  size_t pout = (size_t)epos[e] * H;
#pragma unroll
  for (int h = 0; h < H; ++h) {
    float sc = ssrc[(size_t)s * H + h] + strg[(size_t)g * H + h] + p * c[h];
    sc = sc > 0.f ? sc : 0.2f * sc;
    exps[pout + h] = __expf(sc);
  }
}

// ---------------------------------------------------------------------------
// Aggregation: one wave per target node. Pass 1: denom per head (in-register,
// sequential exps reads). Pass 2: gather proj[srcp[i]] (coalesced 512B/edge)
// * att, accumulate. Epilogue fused: + skip + bias, ELU. No atomics.
// ---------------------------------------------------------------------------
template <int H, int F>
__global__ void aggregate(const int* __restrict__ srcp, const int* __restrict__ row_off,
                          const float* __restrict__ exps, const float* __restrict__ proj,
                          const float* __restrict__ skip, const float* __restrict__ bias,
                          float* __restrict__ out, int N) {
  int wid = (blockIdx.x * blockDim.x + threadIdx.x) >> 6;
  if (wid >= N) return;
  const int lane = threadIdx.x & 63;
  const int f0 = lane * 2;          // each lane owns 2 consecutive features
  const int h = f0 / F;             // head of this lane (F even -> both feats same head)
  const int beg = row_off[wid];
  const int end = row_off[wid + 1];

  float denom = 0.f;
  for (int i = beg; i < end; ++i) denom += exps[(size_t)i * H + h];
  float inv = 1.0f / (denom + 1e-16f);

  float acc0 = 0.f, acc1 = 0.f;
  for (int i = beg; i < end; ++i) {
    float w = exps[(size_t)i * H + h] * inv;
    int s = srcp[i];
    float2 pv = *reinterpret_cast<const float2*>(proj + (size_t)s * (H * F) + f0);
    acc0 += pv.x * w;
    acc1 += pv.y * w;
  }
  size_t base = (size_t)wid * (H * F) + f0;
  float o0 = acc0 + skip[base] + bias[f0];
  float o1 = acc1 + skip[base + 1] + bias[f0 + 1];
  o0 = o0 > 0.f ? o0 : __expf(o0) - 1.f;  // ELU(alpha=1)
  o1 = o1 > 0.f ? o1 : __expf(o1) - 1.f;
  float2 ov = make_float2(o0, o1);
  *reinterpret_cast<float2*>(out + base) = ov;
}

// ---------------------------------------------------------------------------
extern "C" void kernel_launch(void* const* d_in, const int* in_sizes, int n_in,
                              void* d_out, int out_size, void* d_ws, size_t ws_size,
                              hipStream_t stream) {
  const float* x      = (const float*)d_in[0];
  const int*   ei     = (const int*)  d_in[1];
  const float* ep     = (const float*)d_in[2];
  const float* W1     = (const float*)d_in[3];
  const float* Wt1    = (const float*)d_in[4];
  const float* a_src1 = (const float*)d_in[5];
  const float* a_trg1 = (const float*)d_in[6];
  const float* a_tp1  = (const float*)d_in[7];
  const float* b1     = (const float*)d_in[8];
  const float* Wskip1 = (const float*)d_in[9];
  const float* W2     = (const float*)d_in[10];
  const float* Wt2    = (const float*)d_in[11];
  const float* a_src2 = (const float*)d_in[12];
  const float* a_trg2 = (const float*)d_in[13];
  const float* a_tp2  = (const float*)d_in[14];
  const float* b2     = (const float*)d_in[15];

  const int N = in_sizes[0] / 128;
  const int E = in_sizes[1] / 2;
  const int* srcA = ei;
  const int* trgA = ei + E;

  char* ws = (char*)d_ws;
  size_t off = 0;
  auto alloc = [&](size_t bytes) {
    void* p = ws + off;
    off += (bytes + 255) & ~(size_t)255;
    return p;
  };
  int*   deg     = (int*)  alloc((size_t)N * 4);
  int*   cursor  = (int*)  alloc((size_t)N * 4);
  int*   row_off = (int*)  alloc((size_t)(N + 1) * 4);
  int*   srcp    = (int*)  alloc((size_t)E * 4);
  int*   epos    = (int*)  alloc((size_t)E * 4);
  float* proj    = (float*)alloc((size_t)N * 128 * 4);
  float* skip1   = (float*)alloc((size_t)N * 128 * 4);
  float* hbuf    = (float*)alloc((size_t)N * 128 * 4);
  float* ssrc    = (float*)alloc((size_t)N * 8 * 4);
  float* strg    = (float*)alloc((size_t)N * 8 * 4);
  float* exps    = (float*)alloc((size_t)E * 8 * 4);
  (void)ws_size; (void)n_in; (void)out_size;

  hipMemsetAsync(deg, 0, (size_t)N * 4, stream);
  hipMemsetAsync(cursor, 0, (size_t)N * 4, stream);

  const int eb = (E + 255) / 256;

  // CSR build (shared by both layers)
  count_deg<<<eb, 256, 0, stream>>>(trgA, deg, E);
  scan_offsets<<<1, 1024, 0, stream>>>(deg, row_off, N);
  scatter_csr<<<eb, 256, 0, stream>>>(srcA, trgA, row_off, cursor, srcp, epos, E);

  dim3 gg((N + 63) / 64, 2);

  // -------- Layer 1: H=8, F=16, concat, skip = x @ Wskip1 --------
  gemm128_f32<<<gg, 256, 0, stream>>>(x, W1, proj, N);
  gemm128_f32<<<gg, 256, 0, stream>>>(x, Wskip1, skip1, N);
  node_scores<8, 16><<<(N * 8 + 255) / 256, 256, 0, stream>>>(proj, a_src1, a_trg1, ssrc, strg, N);
  edge_scores<8, 16><<<eb, 256, 0, stream>>>(srcA, trgA, epos, ep, Wt1, a_tp1, ssrc, strg, exps, E);
  aggregate<8, 16><<<(N + 3) / 4, 256, 0, stream>>>(srcp, row_off, exps, proj, skip1, b1, hbuf, N);

  // -------- Layer 2: H=1, F=128, mean (=identity), skip = identity --------
  gemm128_f32<<<gg, 256, 0, stream>>>(hbuf, W2, proj, N);
  node_scores<1, 128><<<(N + 255) / 256, 256, 0, stream>>>(proj, a_src2, a_trg2, ssrc, strg, N);
  edge_scores<1, 128><<<eb, 256, 0, stream>>>(srcA, trgA, epos, ep, Wt2, a_tp2, ssrc, strg, exps, E);
  aggregate<1, 128><<<(N + 3) / 4, 256, 0, stream>>>(srcp, row_off, exps, proj, hbuf, b2,
                                                     (float*)d_out, N);
}

// Round 3
// 604.665 us; speedup vs baseline: 1.2316x; 1.2316x over previous
//
#include <hip/hip_runtime.h>
#include <cstdint>
#include <cstddef>

// ---------------------------------------------------------------------------
// GEMM: C[M,128] = A[M,128] @ B[128,128], fp32 vector ALU, 64x64 LDS tiles.
// (unchanged from passing round)
// ---------------------------------------------------------------------------
__global__ void gemm128_f32(const float* __restrict__ A, const float* __restrict__ B,
                            float* __restrict__ C, int M) {
  __shared__ float As[64][132];
  __shared__ float Bs[128][68];
  const int t = threadIdx.x;      // 256 threads
  const int row0 = blockIdx.x * 64;
  const int col0 = blockIdx.y * 64;

#pragma unroll
  for (int i = 0; i < 8; ++i) {
    int idx = t + i * 256;
    int r = idx >> 5, c4 = idx & 31;
    float4 v = make_float4(0.f, 0.f, 0.f, 0.f);
    if (row0 + r < M) v = *reinterpret_cast<const float4*>(A + (size_t)(row0 + r) * 128 + c4 * 4);
    *reinterpret_cast<float4*>(&As[r][c4 * 4]) = v;
  }
#pragma unroll
  for (int i = 0; i < 8; ++i) {
    int idx = t + i * 256;
    int k = idx >> 4, c4 = idx & 15;
    *reinterpret_cast<float4*>(&Bs[k][c4 * 4]) =
        *reinterpret_cast<const float4*>(B + (size_t)k * 128 + col0 + c4 * 4);
  }
  __syncthreads();

  const int ty = t >> 4, tx = t & 15;
  float acc[4][4] = {};
#pragma unroll 8
  for (int k = 0; k < 128; ++k) {
    float a[4];
#pragma unroll
    for (int i = 0; i < 4; ++i) a[i] = As[ty * 4 + i][k];
    float4 bv = *reinterpret_cast<float4*>(&Bs[k][tx * 4]);
    float b[4] = {bv.x, bv.y, bv.z, bv.w};
#pragma unroll
    for (int i = 0; i < 4; ++i)
#pragma unroll
      for (int j = 0; j < 4; ++j) acc[i][j] += a[i] * b[j];
  }
#pragma unroll
  for (int i = 0; i < 4; ++i) {
    int r = row0 + ty * 4 + i;
    if (r < M) {
      float4 v = make_float4(acc[i][0], acc[i][1], acc[i][2], acc[i][3]);
      *reinterpret_cast<float4*>(C + (size_t)r * 128 + col0 + tx * 4) = v;
    }
  }
}

// ---------------------------------------------------------------------------
// CSR build (unchanged)
// ---------------------------------------------------------------------------
__global__ void count_deg(const int* __restrict__ trg, int* __restrict__ deg, int E) {
  int e = blockIdx.x * blockDim.x + threadIdx.x;
  if (e < E) atomicAdd(&deg[trg[e]], 1);
}

__global__ void scan_offsets(const int* __restrict__ deg, int* __restrict__ row_off, int N) {
  __shared__ int sums[1024];
  const int t = threadIdx.x;
  const int per = (N + 1023) / 1024;
  const int beg = t * per;
  const int end = (beg + per < N) ? beg + per : N;
  int s = 0;
  for (int i = beg; i < end; ++i) s += deg[i];
  sums[t] = s;
  __syncthreads();
  for (int off = 1; off < 1024; off <<= 1) {
    int v = sums[t];
    int add = (t >= off) ? sums[t - off] : 0;
    __syncthreads();
    sums[t] = v + add;
    __syncthreads();
  }
  int excl = (t == 0) ? 0 : sums[t - 1];
  for (int i = beg; i < end; ++i) {
    row_off[i] = excl;
    excl += deg[i];
  }
  if (t == 1023) row_off[N] = sums[1023];
}

__global__ void scatter_csr(const int* __restrict__ src, const int* __restrict__ trg,
                            const int* __restrict__ row_off, int* __restrict__ cursor,
                            int* __restrict__ srcp, int* __restrict__ epos, int E) {
  int e = blockIdx.x * blockDim.x + threadIdx.x;
  if (e >= E) return;
  int n = trg[e];
  int pos = row_off[n] + atomicAdd(&cursor[n], 1);
  srcp[pos] = src[e];
  epos[e] = pos;
}

// ---------------------------------------------------------------------------
// Per-node attention scores (unchanged)
// ---------------------------------------------------------------------------
template <int H, int F>
__global__ void node_scores(const float* __restrict__ proj, const float* __restrict__ a_src,
                            const float* __restrict__ a_trg, float* __restrict__ ssrc,
                            float* __restrict__ strg, int N) {
  int idx = blockIdx.x * blockDim.x + threadIdx.x;
  if (idx >= N * H) return;
  int n = idx / H, h = idx % H;
  const float* p = proj + (size_t)n * (H * F) + h * F;
  const float* as = a_src + h * F;
  const float* at = a_trg + h * F;
  float d1 = 0.f, d2 = 0.f;
#pragma unroll
  for (int f = 0; f < F; f += 4) {
    float4 pv = *reinterpret_cast<const float4*>(p + f);
    float4 av = *reinterpret_cast<const float4*>(as + f);
    float4 tv = *reinterpret_cast<const float4*>(at + f);
    d1 += pv.x * av.x + pv.y * av.y + pv.z * av.z + pv.w * av.w;
    d2 += pv.x * tv.x + pv.y * tv.y + pv.z * tv.z + pv.w * tv.w;
  }
  ssrc[idx] = d1;
  strg[idx] = d2;
}

// ---------------------------------------------------------------------------
// Per-edge exp scores, CSR-ordered output (unchanged)
// ---------------------------------------------------------------------------
template <int H, int F>
__global__ void edge_scores(const int* __restrict__ src, const int* __restrict__ trg,
                            const int* __restrict__ epos, const float* __restrict__ ep,
                            const float* __restrict__ Wt, const float* __restrict__ a_tp,
                            const float* __restrict__ ssrc, const float* __restrict__ strg,
                            float* __restrict__ exps, int E) {
  __shared__ float c[H];
  if (threadIdx.x < H) {
    float a = 0.f;
    for (int f = 0; f < F; ++f) a += Wt[threadIdx.x * F + f] * a_tp[threadIdx.x * F + f];
    c[threadIdx.x] = a;
  }
  __syncthreads();
  int e = blockIdx.x * blockDim.x + threadIdx.x;
  if (e >= E) return;
  int s = src[e], g = trg[e];
  float p = ep[e];
  size_t pout = (size_t)epos[e] * H;
#pragma unroll
  for (int h = 0; h < H; ++h) {
    float sc = ssrc[(size_t)s * H + h] + strg[(size_t)g * H + h] + p * c[h];
    sc = sc > 0.f ? sc : 0.2f * sc;
    exps[pout + h] = __expf(sc);
  }
}

// ---------------------------------------------------------------------------
// Aggregation v2: one wave per target node, SINGLE fused pass.
//   - lanes 0-31 = wave-half 0, lanes 32-63 = half 1; each half owns all 128
//     features as float4/lane (32 lanes x 16B = 512B coalesced row read).
//   - each iteration processes 2 edges (one per half); body unrolled x2
//     -> 4 independent 512B gathers in flight per wave.
//   - unnormalized accumulate; divide by denom at the end (re-association).
//   - cross-half combine via __shfl_xor(...,32); half 0 writes the row.
// ---------------------------------------------------------------------------
template <int H, int F>
__global__ void aggregate(const int* __restrict__ srcp, const int* __restrict__ row_off,
                          const float* __restrict__ exps, const float* __restrict__ proj,
                          const float* __restrict__ skip, const float* __restrict__ bias,
                          float* __restrict__ out, int N) {
  int wid = (blockIdx.x * blockDim.x + threadIdx.x) >> 6;
  if (wid >= N) return;
  const int lane = threadIdx.x & 63;
  const int half = lane >> 5;        // 0 or 1
  const int fl = (lane & 31) * 4;    // feature base, 4 consecutive features
  const int h = fl / F;              // F multiple of 4 -> all 4 features same head
  const int beg = row_off[wid];
  const int end = row_off[wid + 1];

  float ax = 0.f, ay = 0.f, az = 0.f, aw = 0.f;
  float denom = 0.f;

  for (int i = beg; i < end; i += 4) {
    int i0 = i + half;       // edges {i, i+1}
    int i1 = i + 2 + half;   // edges {i+2, i+3}
    bool v0 = i0 < end;
    bool v1 = i1 < end;
    int s0 = v0 ? srcp[i0] : 0;
    int s1 = v1 ? srcp[i1] : 0;
    float e0 = v0 ? exps[(size_t)i0 * H + h] : 0.f;
    float e1 = v1 ? exps[(size_t)i1 * H + h] : 0.f;
    float4 p0 = *reinterpret_cast<const float4*>(proj + (size_t)s0 * (H * F) + fl);
    float4 p1 = *reinterpret_cast<const float4*>(proj + (size_t)s1 * (H * F) + fl);
    denom += e0 + e1;
    ax += p0.x * e0 + p1.x * e1;
    ay += p0.y * e0 + p1.y * e1;
    az += p0.z * e0 + p1.z * e1;
    aw += p0.w * e0 + p1.w * e1;
  }

  // combine the two halves (each processed a disjoint set of edges)
  denom += __shfl_xor(denom, 32);
  ax += __shfl_xor(ax, 32);
  ay += __shfl_xor(ay, 32);
  az += __shfl_xor(az, 32);
  aw += __shfl_xor(aw, 32);

  if (half == 0) {
    float inv = 1.0f / (denom + 1e-16f);
    size_t base = (size_t)wid * (H * F) + fl;
    float4 sk = *reinterpret_cast<const float4*>(skip + base);
    float4 bi = *reinterpret_cast<const float4*>(bias + fl);
    float o0 = ax * inv + sk.x + bi.x;
    float o1 = ay * inv + sk.y + bi.y;
    float o2 = az * inv + sk.z + bi.z;
    float o3 = aw * inv + sk.w + bi.w;
    o0 = o0 > 0.f ? o0 : __expf(o0) - 1.f;
    o1 = o1 > 0.f ? o1 : __expf(o1) - 1.f;
    o2 = o2 > 0.f ? o2 : __expf(o2) - 1.f;
    o3 = o3 > 0.f ? o3 : __expf(o3) - 1.f;
    float4 ov = make_float4(o0, o1, o2, o3);
    *reinterpret_cast<float4*>(out + base) = ov;
  }
}

// ---------------------------------------------------------------------------
extern "C" void kernel_launch(void* const* d_in, const int* in_sizes, int n_in,
                              void* d_out, int out_size, void* d_ws, size_t ws_size,
                              hipStream_t stream) {
  const float* x      = (const float*)d_in[0];
  const int*   ei     = (const int*)  d_in[1];
  const float* ep     = (const float*)d_in[2];
  const float* W1     = (const float*)d_in[3];
  const float* Wt1    = (const float*)d_in[4];
  const float* a_src1 = (const float*)d_in[5];
  const float* a_trg1 = (const float*)d_in[6];
  const float* a_tp1  = (const float*)d_in[7];
  const float* b1     = (const float*)d_in[8];
  const float* Wskip1 = (const float*)d_in[9];
  const float* W2     = (const float*)d_in[10];
  const float* Wt2    = (const float*)d_in[11];
  const float* a_src2 = (const float*)d_in[12];
  const float* a_trg2 = (const float*)d_in[13];
  const float* a_tp2  = (const float*)d_in[14];
  const float* b2     = (const float*)d_in[15];

  const int N = in_sizes[0] / 128;
  const int E = in_sizes[1] / 2;
  const int* srcA = ei;
  const int* trgA = ei + E;

  char* ws = (char*)d_ws;
  size_t off = 0;
  auto alloc = [&](size_t bytes) {
    void* p = ws + off;
    off += (bytes + 255) & ~(size_t)255;
    return p;
  };
  int*   deg     = (int*)  alloc((size_t)N * 4);
  int*   cursor  = (int*)  alloc((size_t)N * 4);
  int*   row_off = (int*)  alloc((size_t)(N + 1) * 4);
  int*   srcp    = (int*)  alloc((size_t)E * 4);
  int*   epos    = (int*)  alloc((size_t)E * 4);
  float* proj    = (float*)alloc((size_t)N * 128 * 4);
  float* skip1   = (float*)alloc((size_t)N * 128 * 4);
  float* hbuf    = (float*)alloc((size_t)N * 128 * 4);
  float* ssrc    = (float*)alloc((size_t)N * 8 * 4);
  float* strg    = (float*)alloc((size_t)N * 8 * 4);
  float* exps    = (float*)alloc((size_t)E * 8 * 4);
  (void)ws_size; (void)n_in; (void)out_size;

  hipMemsetAsync(deg, 0, (size_t)N * 4, stream);
  hipMemsetAsync(cursor, 0, (size_t)N * 4, stream);

  const int eb = (E + 255) / 256;

  // CSR build (shared by both layers)
  count_deg<<<eb, 256, 0, stream>>>(trgA, deg, E);
  scan_offsets<<<1, 1024, 0, stream>>>(deg, row_off, N);
  scatter_csr<<<eb, 256, 0, stream>>>(srcA, trgA, row_off, cursor, srcp, epos, E);

  dim3 gg((N + 63) / 64, 2);

  // -------- Layer 1: H=8, F=16, concat, skip = x @ Wskip1 --------
  gemm128_f32<<<gg, 256, 0, stream>>>(x, W1, proj, N);
  gemm128_f32<<<gg, 256, 0, stream>>>(x, Wskip1, skip1, N);
  node_scores<8, 16><<<(N * 8 + 255) / 256, 256, 0, stream>>>(proj, a_src1, a_trg1, ssrc, strg, N);
  edge_scores<8, 16><<<eb, 256, 0, stream>>>(srcA, trgA, epos, ep, Wt1, a_tp1, ssrc, strg, exps, E);
  aggregate<8, 16><<<(N + 3) / 4, 256, 0, stream>>>(srcp, row_off, exps, proj, skip1, b1, hbuf, N);

  // -------- Layer 2: H=1, F=128, mean (=identity), skip = identity --------
  gemm128_f32<<<gg, 256, 0, stream>>>(hbuf, W2, proj, N);
  node_scores<1, 128><<<(N + 255) / 256, 256, 0, stream>>>(proj, a_src2, a_trg2, ssrc, strg, N);
  edge_scores<1, 128><<<eb, 256, 0, stream>>>(srcA, trgA, epos, ep, Wt2, a_tp2, ssrc, strg, exps, E);
  aggregate<1, 128><<<(N + 3) / 4, 256, 0, stream>>>(srcp, row_off, exps, proj, hbuf, b2,
                                                     (float*)d_out, N);
}

// Round 4
// 586.197 us; speedup vs baseline: 1.2704x; 1.0315x over previous
//
#include <hip/hip_runtime.h>
#include <cstdint>
#include <cstddef>

// ---------------------------------------------------------------------------
// GEMM: C[M,128] = A[M,128] @ B[128,128], fp32, 64x64 tiles.
// A-tile stored TRANSPOSED in LDS -> per-k fragment reads are 2x ds_read_b128.
// ---------------------------------------------------------------------------
__global__ void gemm128_f32(const float* __restrict__ A, const float* __restrict__ B,
                            float* __restrict__ C, int M) {
  __shared__ float Ast[128][68];  // [k][row], stride 68 floats (16B-aligned rows)
  __shared__ float Bs[128][68];   // [k][col]
  const int t = threadIdx.x;      // 256 threads
  const int row0 = blockIdx.x * 64;
  const int col0 = blockIdx.y * 64;

#pragma unroll
  for (int i = 0; i < 8; ++i) {
    int idx = t + i * 256;
    int r = idx >> 5, c4 = idx & 31;     // r: 0..63, c4: 0..31 (col base c4*4)
    float4 v = make_float4(0.f, 0.f, 0.f, 0.f);
    if (row0 + r < M) v = *reinterpret_cast<const float4*>(A + (size_t)(row0 + r) * 128 + c4 * 4);
    Ast[c4 * 4 + 0][r] = v.x;
    Ast[c4 * 4 + 1][r] = v.y;
    Ast[c4 * 4 + 2][r] = v.z;
    Ast[c4 * 4 + 3][r] = v.w;
  }
#pragma unroll
  for (int i = 0; i < 8; ++i) {
    int idx = t + i * 256;
    int k = idx >> 4, c4 = idx & 15;
    *reinterpret_cast<float4*>(&Bs[k][c4 * 4]) =
        *reinterpret_cast<const float4*>(B + (size_t)k * 128 + col0 + c4 * 4);
  }
  __syncthreads();

  const int ty = t >> 4, tx = t & 15;
  float acc[4][4] = {};
#pragma unroll 8
  for (int k = 0; k < 128; ++k) {
    float4 a4 = *reinterpret_cast<float4*>(&Ast[k][ty * 4]);
    float4 b4 = *reinterpret_cast<float4*>(&Bs[k][tx * 4]);
    float a[4] = {a4.x, a4.y, a4.z, a4.w};
    float b[4] = {b4.x, b4.y, b4.z, b4.w};
#pragma unroll
    for (int i = 0; i < 4; ++i)
#pragma unroll
      for (int j = 0; j < 4; ++j) acc[i][j] += a[i] * b[j];
  }
#pragma unroll
  for (int i = 0; i < 4; ++i) {
    int r = row0 + ty * 4 + i;
    if (r < M) {
      float4 v = make_float4(acc[i][0], acc[i][1], acc[i][2], acc[i][3]);
      *reinterpret_cast<float4*>(C + (size_t)r * 128 + col0 + tx * 4) = v;
    }
  }
}

// ---------------------------------------------------------------------------
// CSR build: degree count -> single-block scan -> scatter (src ids + edge_prob
// permuted into CSR order; no epos needed since scores are computed in-agg).
// ---------------------------------------------------------------------------
__global__ void count_deg(const int* __restrict__ trg, int* __restrict__ deg, int E) {
  int e = blockIdx.x * blockDim.x + threadIdx.x;
  if (e < E) atomicAdd(&deg[trg[e]], 1);
}

__global__ void scan_offsets(const int* __restrict__ deg, int* __restrict__ row_off, int N) {
  __shared__ int sums[1024];
  const int t = threadIdx.x;
  const int per = (N + 1023) / 1024;
  const int beg = t * per;
  const int end = (beg + per < N) ? beg + per : N;
  int s = 0;
  for (int i = beg; i < end; ++i) s += deg[i];
  sums[t] = s;
  __syncthreads();
  for (int off = 1; off < 1024; off <<= 1) {
    int v = sums[t];
    int add = (t >= off) ? sums[t - off] : 0;
    __syncthreads();
    sums[t] = v + add;
    __syncthreads();
  }
  int excl = (t == 0) ? 0 : sums[t - 1];
  for (int i = beg; i < end; ++i) {
    row_off[i] = excl;
    excl += deg[i];
  }
  if (t == 1023) row_off[N] = sums[1023];
}

__global__ void scatter_csr(const int* __restrict__ src, const int* __restrict__ trg,
                            const float* __restrict__ ep, const int* __restrict__ row_off,
                            int* __restrict__ cursor, int* __restrict__ srcp,
                            float* __restrict__ epc, int E) {
  int e = blockIdx.x * blockDim.x + threadIdx.x;
  if (e >= E) return;
  int n = trg[e];
  int pos = row_off[n] + atomicAdd(&cursor[n], 1);
  srcp[pos] = src[e];
  epc[pos] = ep[e];
}

// ---------------------------------------------------------------------------
// Per-node attention scores (unchanged)
// ---------------------------------------------------------------------------
template <int H, int F>
__global__ void node_scores(const float* __restrict__ proj, const float* __restrict__ a_src,
                            const float* __restrict__ a_trg, float* __restrict__ ssrc,
                            float* __restrict__ strg, int N) {
  int idx = blockIdx.x * blockDim.x + threadIdx.x;
  if (idx >= N * H) return;
  int n = idx / H, h = idx % H;
  const float* p = proj + (size_t)n * (H * F) + h * F;
  const float* as = a_src + h * F;
  const float* at = a_trg + h * F;
  float d1 = 0.f, d2 = 0.f;
#pragma unroll
  for (int f = 0; f < F; f += 4) {
    float4 pv = *reinterpret_cast<const float4*>(p + f);
    float4 av = *reinterpret_cast<const float4*>(as + f);
    float4 tv = *reinterpret_cast<const float4*>(at + f);
    d1 += pv.x * av.x + pv.y * av.y + pv.z * av.z + pv.w * av.w;
    d2 += pv.x * tv.x + pv.y * tv.y + pv.z * tv.z + pv.w * tv.w;
  }
  ssrc[idx] = d1;
  strg[idx] = d2;
}

// ---------------------------------------------------------------------------
// Fused aggregation: one wave per target node, single pass, edge scores
// computed INLINE (edge_scores kernel eliminated).
//   - lanes 0-31 = half 0, 32-63 = half 1; each half owns all 128 features
//     (float4/lane, 512B coalesced proj row).
//   - 2 edges per half per iter -> 4 independent gathers in flight.
//   - score = ssrc[s][h] + strg[node][h] + ep*c_h; c_h reduced once per wave.
//   - unnormalized accumulate, divide at end; cross-half shfl_xor combine.
// ---------------------------------------------------------------------------
template <int H, int F>
__global__ void aggregate(const int* __restrict__ srcp, const float* __restrict__ epc,
                          const int* __restrict__ row_off, const float* __restrict__ ssrc,
                          const float* __restrict__ strg, const float* __restrict__ Wt,
                          const float* __restrict__ a_tp, const float* __restrict__ proj,
                          const float* __restrict__ skip, const float* __restrict__ bias,
                          float* __restrict__ out, int N) {
  int wid = (blockIdx.x * blockDim.x + threadIdx.x) >> 6;
  if (wid >= N) return;
  const int lane = threadIdx.x & 63;
  const int half = lane >> 5;        // 0 or 1
  const int fl = (lane & 31) * 4;    // feature base (4 consecutive features)
  const int h = fl / F;              // this lane's head

  // c_h = <Wt[h,:], a_tp[h,:]> : partial over this lane's 4 features, then
  // shfl-reduce across the F/4 lanes sharing head h (group is xor-closed).
  float4 wt4 = *reinterpret_cast<const float4*>(Wt + fl);
  float4 at4 = *reinterpret_cast<const float4*>(a_tp + fl);
  float ch = wt4.x * at4.x + wt4.y * at4.y + wt4.z * at4.z + wt4.w * at4.w;
#pragma unroll
  for (int off = 1; off < (F / 4); off <<= 1) ch += __shfl_xor(ch, off);

  const float mt = strg[(size_t)wid * H + h];  // target-node score, this head
  const int beg = row_off[wid];
  const int end = row_off[wid + 1];

  float ax = 0.f, ay = 0.f, az = 0.f, aw = 0.f;
  float denom = 0.f;

  for (int i = beg; i < end; i += 4) {
    int i0 = i + half;       // edges {i, i+1}
    int i1 = i + 2 + half;   // edges {i+2, i+3}
    bool v0 = i0 < end;
    bool v1 = i1 < end;
    int s0 = v0 ? srcp[i0] : 0;
    int s1 = v1 ? srcp[i1] : 0;
    float pe0 = v0 ? epc[i0] : 0.f;
    float pe1 = v1 ? epc[i1] : 0.f;
    float ss0 = ssrc[(size_t)s0 * H + h];
    float ss1 = ssrc[(size_t)s1 * H + h];
    float4 p0 = *reinterpret_cast<const float4*>(proj + (size_t)s0 * (H * F) + fl);
    float4 p1 = *reinterpret_cast<const float4*>(proj + (size_t)s1 * (H * F) + fl);
    float sc0 = ss0 + mt + pe0 * ch;
    float sc1 = ss1 + mt + pe1 * ch;
    sc0 = sc0 > 0.f ? sc0 : 0.2f * sc0;
    sc1 = sc1 > 0.f ? sc1 : 0.2f * sc1;
    float e0 = v0 ? __expf(sc0) : 0.f;
    float e1 = v1 ? __expf(sc1) : 0.f;
    denom += e0 + e1;
    ax += p0.x * e0 + p1.x * e1;
    ay += p0.y * e0 + p1.y * e1;
    az += p0.z * e0 + p1.z * e1;
    aw += p0.w * e0 + p1.w * e1;
  }

  denom += __shfl_xor(denom, 32);
  ax += __shfl_xor(ax, 32);
  ay += __shfl_xor(ay, 32);
  az += __shfl_xor(az, 32);
  aw += __shfl_xor(aw, 32);

  if (half == 0) {
    float inv = 1.0f / (denom + 1e-16f);
    size_t base = (size_t)wid * (H * F) + fl;
    float4 sk = *reinterpret_cast<const float4*>(skip + base);
    float4 bi = *reinterpret_cast<const float4*>(bias + fl);
    float o0 = ax * inv + sk.x + bi.x;
    float o1 = ay * inv + sk.y + bi.y;
    float o2 = az * inv + sk.z + bi.z;
    float o3 = aw * inv + sk.w + bi.w;
    o0 = o0 > 0.f ? o0 : __expf(o0) - 1.f;
    o1 = o1 > 0.f ? o1 : __expf(o1) - 1.f;
    o2 = o2 > 0.f ? o2 : __expf(o2) - 1.f;
    o3 = o3 > 0.f ? o3 : __expf(o3) - 1.f;
    float4 ov = make_float4(o0, o1, o2, o3);
    *reinterpret_cast<float4*>(out + base) = ov;
  }
}

// ---------------------------------------------------------------------------
extern "C" void kernel_launch(void* const* d_in, const int* in_sizes, int n_in,
                              void* d_out, int out_size, void* d_ws, size_t ws_size,
                              hipStream_t stream) {
  const float* x      = (const float*)d_in[0];
  const int*   ei     = (const int*)  d_in[1];
  const float* ep     = (const float*)d_in[2];
  const float* W1     = (const float*)d_in[3];
  const float* Wt1    = (const float*)d_in[4];
  const float* a_src1 = (const float*)d_in[5];
  const float* a_trg1 = (const float*)d_in[6];
  const float* a_tp1  = (const float*)d_in[7];
  const float* b1     = (const float*)d_in[8];
  const float* Wskip1 = (const float*)d_in[9];
  const float* W2     = (const float*)d_in[10];
  const float* Wt2    = (const float*)d_in[11];
  const float* a_src2 = (const float*)d_in[12];
  const float* a_trg2 = (const float*)d_in[13];
  const float* a_tp2  = (const float*)d_in[14];
  const float* b2     = (const float*)d_in[15];

  const int N = in_sizes[0] / 128;
  const int E = in_sizes[1] / 2;
  const int* srcA = ei;
  const int* trgA = ei + E;

  char* ws = (char*)d_ws;
  size_t off = 0;
  auto alloc = [&](size_t bytes) {
    void* p = ws + off;
    off += (bytes + 255) & ~(size_t)255;
    return p;
  };
  int*   degcur  = (int*)  alloc((size_t)2 * N * 4);  // deg | cursor (one memset)
  int*   deg     = degcur;
  int*   cursor  = degcur + N;
  int*   row_off = (int*)  alloc((size_t)(N + 1) * 4);
  int*   srcp    = (int*)  alloc((size_t)E * 4);
  float* epc     = (float*)alloc((size_t)E * 4);
  float* proj    = (float*)alloc((size_t)N * 128 * 4);
  float* skip1   = (float*)alloc((size_t)N * 128 * 4);
  float* hbuf    = (float*)alloc((size_t)N * 128 * 4);
  float* ssrc    = (float*)alloc((size_t)N * 8 * 4);
  float* strg    = (float*)alloc((size_t)N * 8 * 4);
  (void)ws_size; (void)n_in; (void)out_size;

  hipMemsetAsync(degcur, 0, (size_t)2 * N * 4, stream);

  const int eb = (E + 255) / 256;

  // CSR build (shared by both layers)
  count_deg<<<eb, 256, 0, stream>>>(trgA, deg, E);
  scan_offsets<<<1, 1024, 0, stream>>>(deg, row_off, N);
  scatter_csr<<<eb, 256, 0, stream>>>(srcA, trgA, ep, row_off, cursor, srcp, epc, E);

  dim3 gg((N + 63) / 64, 2);

  // -------- Layer 1: H=8, F=16, concat, skip = x @ Wskip1 --------
  gemm128_f32<<<gg, 256, 0, stream>>>(x, W1, proj, N);
  gemm128_f32<<<gg, 256, 0, stream>>>(x, Wskip1, skip1, N);
  node_scores<8, 16><<<(N * 8 + 255) / 256, 256, 0, stream>>>(proj, a_src1, a_trg1, ssrc, strg, N);
  aggregate<8, 16><<<(N + 3) / 4, 256, 0, stream>>>(srcp, epc, row_off, ssrc, strg, Wt1, a_tp1,
                                                    proj, skip1, b1, hbuf, N);

  // -------- Layer 2: H=1, F=128, mean (=identity), skip = identity --------
  gemm128_f32<<<gg, 256, 0, stream>>>(hbuf, W2, proj, N);
  node_scores<1, 128><<<(N + 255) / 256, 256, 0, stream>>>(proj, a_src2, a_trg2, ssrc, strg, N);
  aggregate<1, 128><<<(N + 3) / 4, 256, 0, stream>>>(srcp, epc, row_off, ssrc, strg, Wt2, a_tp2,
                                                     proj, hbuf, b2, (float*)d_out, N);
}